// Round 1
// baseline (929.759 us; speedup 1.0000x reference)
//
#include <hip/hip_runtime.h>

// ---------------------------------------------------------------- types
typedef __bf16 bf16;
typedef __bf16 bf16x8 __attribute__((ext_vector_type(8)));
typedef __bf16 bf16x4 __attribute__((ext_vector_type(4)));
typedef float  f32x4  __attribute__((ext_vector_type(4)));

#define T_TOK   8192
#define DM      1024
#define DFF     4096
#define NE      8
#define CAP     8192          // max tokens per expert
#define NPAIR   16384         // total pairs (T*2)

// ---------------------------------------------------------------- ws layout (bytes)
#define CNT_OFF    0u
#define OFFS_OFF   32u
#define USAGE_OFF  64u
#define TLIST_OFF  256u                       // int[NE*CAP]            = 262144
#define TOKEXP_OFF (TLIST_OFF + 262144u)      // int[2*T]               = 65536
#define TOKW_OFF   (TOKEXP_OFF + 65536u)      // float[2*T]             = 65536
#define PAIR_OFF   (TOKW_OFF + 65536u)        // int[2*T]               = 65536
#define XB_OFF     (1u<<20)                   // bf16[T*DM]             = 16777216
#define W1T_OFF    (XB_OFF + 16777216u)       // bf16[NE*DFF*DM]        = 67108864
#define W2T_OFF    (W1T_OFF + 67108864u)      // bf16[NE*DM*DFF]        = 67108864
#define H_OFF      (W2T_OFF + 67108864u)      // bf16[NPAIR*DFF]        = 134217728
#define YB_OFF     (H_OFF + 134217728u)       // bf16[NPAIR*DM]         = 33554432

// ---------------------------------------------------------------- helpers
__device__ __forceinline__ void gload_lds16(const void* g, void* l) {
    __builtin_amdgcn_global_load_lds(
        (const __attribute__((address_space(1))) unsigned int*)g,
        (__attribute__((address_space(3))) unsigned int*)l,
        16, 0, 0);
}

// ---------------------------------------------------------------- gate (fp32, wave per token)
__global__ __launch_bounds__(1024)
void gate_kernel(const float* __restrict__ x, const float* __restrict__ Wg,
                 const float* __restrict__ bg, int* __restrict__ tokexp,
                 float* __restrict__ tokw, float* __restrict__ usage)
{
    __shared__ float blkp[NE];
    const int t = threadIdx.x;
    const int wave = t >> 6, lane = t & 63;
    if (t < NE) blkp[t] = 0.f;
    __syncthreads();

    const int token = blockIdx.x * 16 + wave;
    const float* xrow = x + (size_t)token * DM;
    float acc[NE] = {0.f,0.f,0.f,0.f,0.f,0.f,0.f,0.f};
    for (int u = 0; u < 16; ++u) {
        float xv = xrow[lane + 64*u];
        const float4* wg4 = (const float4*)(Wg + (size_t)(lane + 64*u) * NE);
        float4 wa = wg4[0], wb = wg4[1];
        acc[0] += xv*wa.x; acc[1] += xv*wa.y; acc[2] += xv*wa.z; acc[3] += xv*wa.w;
        acc[4] += xv*wb.x; acc[5] += xv*wb.y; acc[6] += xv*wb.z; acc[7] += xv*wb.w;
    }
    #pragma unroll
    for (int e = 0; e < NE; ++e) {
        float v = acc[e];
        #pragma unroll
        for (int off = 32; off > 0; off >>= 1) v += __shfl_down(v, off, 64);
        acc[e] = v;
    }
    if (lane == 0) {
        float lg[NE];
        #pragma unroll
        for (int e = 0; e < NE; ++e) lg[e] = acc[e] + bg[e];
        int e0 = 0; float l0 = lg[0];
        #pragma unroll
        for (int e = 1; e < NE; ++e) if (lg[e] > l0) { l0 = lg[e]; e0 = e; }
        int e1 = -1; float l1 = -1e30f;
        #pragma unroll
        for (int e = 0; e < NE; ++e) if (e != e0 && lg[e] > l1) { l1 = lg[e]; e1 = e; }
        float a  = expf(l1 - l0);
        float w0 = 1.f / (1.f + a);
        float w1 = a * w0;
        // full softmax for aux loss
        float s = 0.f, pe[NE];
        #pragma unroll
        for (int e = 0; e < NE; ++e) { pe[e] = expf(lg[e] - l0); s += pe[e]; }
        float inv = 1.f / s;
        #pragma unroll
        for (int e = 0; e < NE; ++e) atomicAdd(&blkp[e], pe[e] * inv);
        tokexp[2*token]   = e0;  tokexp[2*token+1] = e1;
        tokw[2*token]     = w0;  tokw[2*token+1]   = w1;
    }
    __syncthreads();
    if (t < NE) atomicAdd(&usage[t], blkp[t]);
}

// ---------------------------------------------------------------- list build (block-aggregated atomics)
__global__ __launch_bounds__(256)
void build_lists_kernel(const int* __restrict__ tokexp, const float* __restrict__ tokw,
                        int* __restrict__ counts, int* __restrict__ tlist,
                        int* __restrict__ pairpos)
{
    __shared__ int lcnt[NE], lbase[NE];
    const int t = threadIdx.x;
    const int token = blockIdx.x * 256 + t;
    if (t < NE) lcnt[t] = 0;
    __syncthreads();
    int e0 = tokexp[2*token], e1 = tokexp[2*token+1];
    int s0 = atomicAdd(&lcnt[e0], 1);
    int s1 = atomicAdd(&lcnt[e1], 1);
    __syncthreads();
    if (t < NE) lbase[t] = atomicAdd(&counts[t], lcnt[t]);
    __syncthreads();
    int p0 = lbase[e0] + s0, p1 = lbase[e1] + s1;
    tlist[e0*CAP + p0] = token;
    tlist[e1*CAP + p1] = token;
    pairpos[2*token]   = (e0 << 13) | p0;
    pairpos[2*token+1] = (e1 << 13) | p1;
}

// ---------------------------------------------------------------- offsets + aux loss
__global__ void offsets_aux_kernel(const int* __restrict__ counts, const float* __restrict__ usage,
                                   int* __restrict__ offs, float* __restrict__ aux_out)
{
    if (threadIdx.x == 0 && blockIdx.x == 0) {
        int o = 0;
        for (int e = 0; e < NE; ++e) { offs[e] = o; o += counts[e]; }
        float aux = 0.f;
        for (int e = 0; e < NE; ++e) { float u = usage[e] * (1.f/8192.f); aux += u*u; }
        *aux_out = aux * 8.f;
    }
}

// ---------------------------------------------------------------- x -> bf16
__global__ __launch_bounds__(256)
void cvt_x_kernel(const float* __restrict__ x, bf16* __restrict__ xb)
{
    const size_t i = (size_t)(blockIdx.x * 256 + threadIdx.x);
    float4 v = ((const float4*)x)[i];
    bf16x4 o = { (bf16)v.x, (bf16)v.y, (bf16)v.z, (bf16)v.w };
    ((bf16x4*)xb)[i] = o;
}

// ---------------------------------------------------------------- transpose + cvt: src f32 [R][C] -> dst bf16 [C][R] per expert
__global__ __launch_bounds__(256)
void transpose_cvt_kernel(const float* __restrict__ src, bf16* __restrict__ dst, int R, int C)
{
    const int e = blockIdx.z;
    src += (size_t)e * R * C;
    dst += (size_t)e * R * C;
    const int c0 = blockIdx.x * 64, r0 = blockIdx.y * 64;
    __shared__ float tile[64][65];
    const int tx = threadIdx.x & 63, ty = threadIdx.x >> 6;
    #pragma unroll
    for (int i = 0; i < 16; ++i) {
        int r = i*4 + ty;
        tile[r][tx] = src[(size_t)(r0 + r) * C + c0 + tx];
    }
    __syncthreads();
    #pragma unroll
    for (int i = 0; i < 16; ++i) {
        int r = i*4 + ty;
        dst[(size_t)(c0 + r) * R + r0 + tx] = (bf16)tile[tx][r];
    }
}

// ---------------------------------------------------------------- GEMM1: h = relu(gather(xb) @ W1 + b1), bf16 out
__global__ __launch_bounds__(256)
void gemm1_kernel(const bf16* __restrict__ xb, const bf16* __restrict__ w1t,
                  const float* __restrict__ b1, const int* __restrict__ counts,
                  const int* __restrict__ offs, const int* __restrict__ tlist,
                  bf16* __restrict__ h)
{
    const int e   = blockIdx.z;
    const int cnt = counts[e];
    const int m0  = blockIdx.y * 128;
    if (m0 >= cnt) return;
    const int n0  = blockIdx.x * 128;
    const int ofe = offs[e];

    __shared__ __align__(16) bf16 As[128*64];
    __shared__ __align__(16) bf16 Bs[128*64];
    __shared__ int toks[128];

    const int t = threadIdx.x;
    if (t < 128) {
        int slot = m0 + t;
        toks[t] = tlist[e*CAP + (slot < cnt ? slot : cnt-1)];
    }
    __syncthreads();

    const bf16* gA[4]; const bf16* gB[4]; int ldso[4];
    #pragma unroll
    for (int j = 0; j < 4; ++j) {
        int c = j*256 + t;
        ldso[j] = c * 8;
        int row = c >> 3, cc = c & 7;
        gA[j] = xb  + (size_t)toks[row] * DM + cc*8;
        gB[j] = w1t + ((size_t)e*DFF + n0 + row) * DM + cc*8;
    }

    const int lane = t & 63, wv = t >> 6;
    const int wr = wv >> 1, wc = wv & 1;
    const int fr = lane & 15, fq = lane >> 4;
    f32x4 acc[4][4] = {};

    for (int k0 = 0; k0 < DM; k0 += 64) {
        __syncthreads();
        #pragma unroll
        for (int j = 0; j < 4; ++j) {
            gload_lds16(gA[j] + k0, &As[ldso[j]]);
            gload_lds16(gB[j] + k0, &Bs[ldso[j]]);
        }
        __syncthreads();
        #pragma unroll
        for (int ks = 0; ks < 2; ++ks) {
            bf16x8 af[4], bb[4];
            #pragma unroll
            for (int i = 0; i < 4; ++i)
                af[i] = *(const bf16x8*)&As[(wr*64 + i*16 + fr)*64 + ks*32 + fq*8];
            #pragma unroll
            for (int j = 0; j < 4; ++j)
                bb[j] = *(const bf16x8*)&Bs[(wc*64 + j*16 + fr)*64 + ks*32 + fq*8];
            #pragma unroll
            for (int i = 0; i < 4; ++i)
                #pragma unroll
                for (int j = 0; j < 4; ++j)
                    acc[i][j] = __builtin_amdgcn_mfma_f32_16x16x32_bf16(af[i], bb[j], acc[i][j], 0, 0, 0);
        }
    }

    float bias[4];
    #pragma unroll
    for (int j = 0; j < 4; ++j) bias[j] = b1[(size_t)e*DFF + n0 + wc*64 + j*16 + fr];
    #pragma unroll
    for (int i = 0; i < 4; ++i) {
        #pragma unroll
        for (int r = 0; r < 4; ++r) {
            int slot = m0 + wr*64 + i*16 + fq*4 + r;
            if (slot < cnt) {
                size_t hrow = (size_t)(ofe + slot);
                #pragma unroll
                for (int j = 0; j < 4; ++j) {
                    float v = acc[i][j][r] + bias[j];
                    h[hrow*DFF + n0 + wc*64 + j*16 + fr] = (bf16)fmaxf(v, 0.f);
                }
            }
        }
    }
}

// ---------------------------------------------------------------- GEMM2: yb = h @ W2 + b2, bf16 out (per pair-row)
__global__ __launch_bounds__(256)
void gemm2_kernel(const bf16* __restrict__ h, const bf16* __restrict__ w2t,
                  const float* __restrict__ b2, const int* __restrict__ counts,
                  const int* __restrict__ offs, bf16* __restrict__ yb)
{
    const int e   = blockIdx.z;
    const int cnt = counts[e];
    const int m0  = blockIdx.y * 128;
    if (m0 >= cnt) return;
    const int n0  = blockIdx.x * 128;
    const int ofe = offs[e];

    __shared__ __align__(16) bf16 As[128*64];
    __shared__ __align__(16) bf16 Bs[128*64];

    const int t = threadIdx.x;
    const bf16* gA[4]; const bf16* gB[4]; int ldso[4];
    #pragma unroll
    for (int j = 0; j < 4; ++j) {
        int c = j*256 + t;
        ldso[j] = c * 8;
        int row = c >> 3, cc = c & 7;
        int arow = m0 + row; if (arow > cnt-1) arow = cnt-1;
        gA[j] = h   + ((size_t)ofe + arow) * DFF + cc*8;
        gB[j] = w2t + ((size_t)e*DM + n0 + row) * DFF + cc*8;
    }

    const int lane = t & 63, wv = t >> 6;
    const int wr = wv >> 1, wc = wv & 1;
    const int fr = lane & 15, fq = lane >> 4;
    f32x4 acc[4][4] = {};

    for (int k0 = 0; k0 < DFF; k0 += 64) {
        __syncthreads();
        #pragma unroll
        for (int j = 0; j < 4; ++j) {
            gload_lds16(gA[j] + k0, &As[ldso[j]]);
            gload_lds16(gB[j] + k0, &Bs[ldso[j]]);
        }
        __syncthreads();
        #pragma unroll
        for (int ks = 0; ks < 2; ++ks) {
            bf16x8 af[4], bb[4];
            #pragma unroll
            for (int i = 0; i < 4; ++i)
                af[i] = *(const bf16x8*)&As[(wr*64 + i*16 + fr)*64 + ks*32 + fq*8];
            #pragma unroll
            for (int j = 0; j < 4; ++j)
                bb[j] = *(const bf16x8*)&Bs[(wc*64 + j*16 + fr)*64 + ks*32 + fq*8];
            #pragma unroll
            for (int i = 0; i < 4; ++i)
                #pragma unroll
                for (int j = 0; j < 4; ++j)
                    acc[i][j] = __builtin_amdgcn_mfma_f32_16x16x32_bf16(af[i], bb[j], acc[i][j], 0, 0, 0);
        }
    }

    float bias[4];
    #pragma unroll
    for (int j = 0; j < 4; ++j) bias[j] = b2[(size_t)e*DM + n0 + wc*64 + j*16 + fr];
    #pragma unroll
    for (int i = 0; i < 4; ++i) {
        #pragma unroll
        for (int r = 0; r < 4; ++r) {
            int slot = m0 + wr*64 + i*16 + fq*4 + r;
            if (slot < cnt) {
                size_t yrow = (size_t)(ofe + slot);
                #pragma unroll
                for (int j = 0; j < 4; ++j) {
                    float v = acc[i][j][r] + bias[j];
                    yb[yrow*DM + n0 + wc*64 + j*16 + fr] = (bf16)v;
                }
            }
        }
    }
}

// ---------------------------------------------------------------- combine: out[t] = w0*y[row0] + w1*y[row1]
__global__ __launch_bounds__(256)
void combine_kernel(const bf16* __restrict__ yb, const int* __restrict__ pairpos,
                    const float* __restrict__ tokw, const int* __restrict__ offs,
                    float* __restrict__ out)
{
    const int i   = blockIdx.x * 256 + threadIdx.x;   // 4 floats each
    const int tok = i >> 8;
    const int d4  = (i & 255) * 4;
    int p0 = pairpos[2*tok], p1 = pairpos[2*tok+1];
    float w0 = tokw[2*tok],  w1 = tokw[2*tok+1];
    size_t r0 = (size_t)offs[p0 >> 13] + (p0 & 8191);
    size_t r1 = (size_t)offs[p1 >> 13] + (p1 & 8191);
    bf16x4 y0 = *(const bf16x4*)&yb[r0*DM + d4];
    bf16x4 y1 = *(const bf16x4*)&yb[r1*DM + d4];
    float4 o;
    o.x = w0*(float)y0[0] + w1*(float)y1[0];
    o.y = w0*(float)y0[1] + w1*(float)y1[1];
    o.z = w0*(float)y0[2] + w1*(float)y1[2];
    o.w = w0*(float)y0[3] + w1*(float)y1[3];
    *(float4*)&out[(size_t)tok*DM + d4] = o;
}

// ---------------------------------------------------------------- launch
extern "C" void kernel_launch(void* const* d_in, const int* in_sizes, int n_in,
                              void* d_out, int out_size, void* d_ws, size_t ws_size,
                              hipStream_t stream)
{
    const float* x  = (const float*)d_in[0];
    const float* Wg = (const float*)d_in[1];
    const float* bg = (const float*)d_in[2];
    const float* W1 = (const float*)d_in[3];
    const float* b1 = (const float*)d_in[4];
    const float* W2 = (const float*)d_in[5];
    const float* b2 = (const float*)d_in[6];
    float* out = (float*)d_out;

    char* wsb = (char*)d_ws;
    int*   counts  = (int*)  (wsb + CNT_OFF);
    int*   offs    = (int*)  (wsb + OFFS_OFF);
    float* usage   = (float*)(wsb + USAGE_OFF);
    int*   tlist   = (int*)  (wsb + TLIST_OFF);
    int*   tokexp  = (int*)  (wsb + TOKEXP_OFF);
    float* tokw    = (float*)(wsb + TOKW_OFF);
    int*   pairpos = (int*)  (wsb + PAIR_OFF);
    bf16*  xb      = (bf16*) (wsb + XB_OFF);
    bf16*  w1t     = (bf16*) (wsb + W1T_OFF);
    bf16*  w2t     = (bf16*) (wsb + W2T_OFF);
    bf16*  hbuf    = (bf16*) (wsb + H_OFF);
    bf16*  ybuf    = (bf16*) (wsb + YB_OFF);

    hipMemsetAsync(wsb, 0, 96, stream);   // counts, offs, usage

    gate_kernel<<<512, 1024, 0, stream>>>(x, Wg, bg, tokexp, tokw, usage);
    build_lists_kernel<<<32, 256, 0, stream>>>(tokexp, tokw, counts, tlist, pairpos);
    offsets_aux_kernel<<<1, 64, 0, stream>>>(counts, usage, offs, out + 8388608);

    cvt_x_kernel<<<8192, 256, 0, stream>>>(x, xb);
    transpose_cvt_kernel<<<dim3(64, 16, NE), 256, 0, stream>>>(W1, w1t, DM, DFF);
    transpose_cvt_kernel<<<dim3(16, 64, NE), 256, 0, stream>>>(W2, w2t, DFF, DM);

    gemm1_kernel<<<dim3(32, 64, NE), 256, 0, stream>>>(xb, w1t, b1, counts, offs, tlist, hbuf);
    gemm2_kernel<<<dim3(8, 64, NE), 256, 0, stream>>>(hbuf, w2t, b2, counts, offs, ybuf);
    combine_kernel<<<8192, 256, 0, stream>>>(ybuf, pairpos, tokw, offs, out);
}

// Round 2
// 765.228 us; speedup vs baseline: 1.2150x; 1.2150x over previous
//
#include <hip/hip_runtime.h>

// ---------------------------------------------------------------- types
typedef __bf16 bf16;
typedef __bf16 bf16x8 __attribute__((ext_vector_type(8)));
typedef __bf16 bf16x4 __attribute__((ext_vector_type(4)));
typedef float  f32x4  __attribute__((ext_vector_type(4)));

#define T_TOK   8192
#define DM      1024
#define DFF     4096
#define NE      8
#define CAP     8192          // max tokens per expert
#define NPAIR   16384         // total pairs (T*2)

// ---------------------------------------------------------------- ws layout (bytes)
#define CNT_OFF    0u
#define OFFS_OFF   32u
#define USAGE_OFF  64u
#define TLIST_OFF  256u                       // int[NE*CAP]            = 262144
#define TOKEXP_OFF (TLIST_OFF + 262144u)      // int[2*T]               = 65536
#define TOKW_OFF   (TOKEXP_OFF + 65536u)      // float[2*T]             = 65536
#define PAIR_OFF   (TOKW_OFF + 65536u)        // int[2*T]               = 65536
#define XB_OFF     (1u<<20)                   // bf16[T*DM]             = 16777216
#define W1T_OFF    (XB_OFF + 16777216u)       // bf16[NE*DFF*DM]        = 67108864
#define W2T_OFF    (W1T_OFF + 67108864u)      // bf16[NE*DM*DFF]        = 67108864
#define H_OFF      (W2T_OFF + 67108864u)      // bf16[NPAIR*DFF]        = 134217728
#define YB_OFF     (H_OFF + 134217728u)       // bf16[NPAIR*DM]         = 33554432

// ---------------------------------------------------------------- helpers
__device__ __forceinline__ void gload_lds16(const void* g, void* l) {
    __builtin_amdgcn_global_load_lds(
        (const __attribute__((address_space(1))) unsigned int*)g,
        (__attribute__((address_space(3))) unsigned int*)l,
        16, 0, 0);
}

// ---------------------------------------------------------------- gate (fp32, wave per token)
__global__ __launch_bounds__(1024)
void gate_kernel(const float* __restrict__ x, const float* __restrict__ Wg,
                 const float* __restrict__ bg, int* __restrict__ tokexp,
                 float* __restrict__ tokw, float* __restrict__ usage)
{
    __shared__ float blkp[NE];
    const int t = threadIdx.x;
    const int wave = t >> 6, lane = t & 63;
    if (t < NE) blkp[t] = 0.f;
    __syncthreads();

    const int token = blockIdx.x * 16 + wave;
    const float* xrow = x + (size_t)token * DM;
    float acc[NE] = {0.f,0.f,0.f,0.f,0.f,0.f,0.f,0.f};
    for (int u = 0; u < 16; ++u) {
        float xv = xrow[lane + 64*u];
        const float4* wg4 = (const float4*)(Wg + (size_t)(lane + 64*u) * NE);
        float4 wa = wg4[0], wb = wg4[1];
        acc[0] += xv*wa.x; acc[1] += xv*wa.y; acc[2] += xv*wa.z; acc[3] += xv*wa.w;
        acc[4] += xv*wb.x; acc[5] += xv*wb.y; acc[6] += xv*wb.z; acc[7] += xv*wb.w;
    }
    #pragma unroll
    for (int e = 0; e < NE; ++e) {
        float v = acc[e];
        #pragma unroll
        for (int off = 32; off > 0; off >>= 1) v += __shfl_down(v, off, 64);
        acc[e] = v;
    }
    if (lane == 0) {
        float lg[NE];
        #pragma unroll
        for (int e = 0; e < NE; ++e) lg[e] = acc[e] + bg[e];
        int e0 = 0; float l0 = lg[0];
        #pragma unroll
        for (int e = 1; e < NE; ++e) if (lg[e] > l0) { l0 = lg[e]; e0 = e; }
        int e1 = -1; float l1 = -1e30f;
        #pragma unroll
        for (int e = 0; e < NE; ++e) if (e != e0 && lg[e] > l1) { l1 = lg[e]; e1 = e; }
        float a  = expf(l1 - l0);
        float w0 = 1.f / (1.f + a);
        float w1 = a * w0;
        float s = 0.f, pe[NE];
        #pragma unroll
        for (int e = 0; e < NE; ++e) { pe[e] = expf(lg[e] - l0); s += pe[e]; }
        float inv = 1.f / s;
        #pragma unroll
        for (int e = 0; e < NE; ++e) atomicAdd(&blkp[e], pe[e] * inv);
        tokexp[2*token]   = e0;  tokexp[2*token+1] = e1;
        tokw[2*token]     = w0;  tokw[2*token+1]   = w1;
    }
    __syncthreads();
    if (t < NE) atomicAdd(&usage[t], blkp[t]);
}

// ---------------------------------------------------------------- list build (block-aggregated atomics)
__global__ __launch_bounds__(256)
void build_lists_kernel(const int* __restrict__ tokexp, const float* __restrict__ tokw,
                        int* __restrict__ counts, int* __restrict__ tlist,
                        int* __restrict__ pairpos)
{
    __shared__ int lcnt[NE], lbase[NE];
    const int t = threadIdx.x;
    const int token = blockIdx.x * 256 + t;
    if (t < NE) lcnt[t] = 0;
    __syncthreads();
    int e0 = tokexp[2*token], e1 = tokexp[2*token+1];
    int s0 = atomicAdd(&lcnt[e0], 1);
    int s1 = atomicAdd(&lcnt[e1], 1);
    __syncthreads();
    if (t < NE) lbase[t] = atomicAdd(&counts[t], lcnt[t]);
    __syncthreads();
    int p0 = lbase[e0] + s0, p1 = lbase[e1] + s1;
    tlist[e0*CAP + p0] = token;
    tlist[e1*CAP + p1] = token;
    pairpos[2*token]   = (e0 << 13) | p0;
    pairpos[2*token+1] = (e1 << 13) | p1;
}

// ---------------------------------------------------------------- offsets + aux loss
__global__ void offsets_aux_kernel(const int* __restrict__ counts, const float* __restrict__ usage,
                                   int* __restrict__ offs, float* __restrict__ aux_out)
{
    if (threadIdx.x == 0 && blockIdx.x == 0) {
        int o = 0;
        for (int e = 0; e < NE; ++e) { offs[e] = o; o += counts[e]; }
        float aux = 0.f;
        for (int e = 0; e < NE; ++e) { float u = usage[e] * (1.f/8192.f); aux += u*u; }
        *aux_out = aux * 8.f;
    }
}

// ---------------------------------------------------------------- x -> bf16
__global__ __launch_bounds__(256)
void cvt_x_kernel(const float* __restrict__ x, bf16* __restrict__ xb)
{
    const size_t i = (size_t)(blockIdx.x * 256 + threadIdx.x);
    float4 v = ((const float4*)x)[i];
    bf16x4 o = { (bf16)v.x, (bf16)v.y, (bf16)v.z, (bf16)v.w };
    ((bf16x4*)xb)[i] = o;
}

// ---------------------------------------------------------------- transpose + cvt (vectorized): f32 [R][C] -> bf16 [C][R]
__global__ __launch_bounds__(256)
void transpose_cvt_kernel(const float* __restrict__ src, bf16* __restrict__ dst, int R, int C)
{
    const int e = blockIdx.z;
    src += (size_t)e * R * C;
    dst += (size_t)e * R * C;
    const int c0 = blockIdx.x * 64, r0 = blockIdx.y * 64;
    __shared__ float tile[64][65];
    const int t = threadIdx.x;
    const int lr = t >> 4, lc4 = (t & 15) * 4;
    #pragma unroll
    for (int rd = 0; rd < 4; ++rd) {
        int r = rd*16 + lr;
        float4 v = *(const float4*)&src[(size_t)(r0 + r) * C + c0 + lc4];
        tile[r][lc4+0] = v.x; tile[r][lc4+1] = v.y;
        tile[r][lc4+2] = v.z; tile[r][lc4+3] = v.w;
    }
    __syncthreads();
    const int dc = t >> 3, r8 = (t & 7) * 8;
    #pragma unroll
    for (int rd = 0; rd < 2; ++rd) {
        int c = rd*32 + dc;
        bf16x8 o;
        #pragma unroll
        for (int k = 0; k < 8; ++k) o[k] = (bf16)tile[r8+k][c];
        *(bf16x8*)&dst[(size_t)(c0 + c) * R + r0 + r8] = o;
    }
}

// ---------------------------------------------------------------- 256x256 8-phase grouped GEMM (T1+T2+T3+T4+T5)
// LDS: A halves [2 dbuf][2 khalf][256 rows][32 k] bf16 = 64 KB, B same = 64 KB, toks 1 KB
// swizzle: 16B-chunk col c16 ^= (row&3)^((row>>2)&3) on BOTH global-src and ds_read (rule #21)

#define STG_A(BUF, HH, TI) do { \
    gload_lds16(aSrc0 + (size_t)(TI)*64 + (HH)*32, smem + ((BUF)*2+(HH))*16384 + t*16); \
    gload_lds16(aSrc1 + (size_t)(TI)*64 + (HH)*32, smem + ((BUF)*2+(HH))*16384 + 8192 + t*16); \
} while(0)

#define STG_B(BUF, HH, TI) do { \
    gload_lds16(bSrc0 + (size_t)(TI)*64 + (HH)*32, smem + 65536 + ((BUF)*2+(HH))*16384 + t*16); \
    gload_lds16(bSrc1 + (size_t)(TI)*64 + (HH)*32, smem + 65536 + ((BUF)*2+(HH))*16384 + 8192 + t*16); \
} while(0)

#define PHASE(B_, HH, RH, STAGE, VM) { \
    const char* Ah = smem + ((B_)*2+(HH))*16384; \
    const char* Bh = smem + 65536 + ((B_)*2+(HH))*16384; \
    bf16x8 af0 = *(const bf16x8*)(Ah + aoff[(RH)*4+0]); \
    bf16x8 af1 = *(const bf16x8*)(Ah + aoff[(RH)*4+1]); \
    bf16x8 af2 = *(const bf16x8*)(Ah + aoff[(RH)*4+2]); \
    bf16x8 af3 = *(const bf16x8*)(Ah + aoff[(RH)*4+3]); \
    if ((RH) == 0) { \
        bfr0 = *(const bf16x8*)(Bh + boff[0]); \
        bfr1 = *(const bf16x8*)(Bh + boff[1]); \
        bfr2 = *(const bf16x8*)(Bh + boff[2]); \
        bfr3 = *(const bf16x8*)(Bh + boff[3]); \
    } \
    STAGE; \
    __builtin_amdgcn_s_barrier(); \
    asm volatile("s_waitcnt lgkmcnt(0)" ::: "memory"); \
    __builtin_amdgcn_s_setprio(1); \
    acc[(RH)*4+0][0] = __builtin_amdgcn_mfma_f32_16x16x32_bf16(af0, bfr0, acc[(RH)*4+0][0], 0,0,0); \
    acc[(RH)*4+1][0] = __builtin_amdgcn_mfma_f32_16x16x32_bf16(af1, bfr0, acc[(RH)*4+1][0], 0,0,0); \
    acc[(RH)*4+2][0] = __builtin_amdgcn_mfma_f32_16x16x32_bf16(af2, bfr0, acc[(RH)*4+2][0], 0,0,0); \
    acc[(RH)*4+3][0] = __builtin_amdgcn_mfma_f32_16x16x32_bf16(af3, bfr0, acc[(RH)*4+3][0], 0,0,0); \
    acc[(RH)*4+0][1] = __builtin_amdgcn_mfma_f32_16x16x32_bf16(af0, bfr1, acc[(RH)*4+0][1], 0,0,0); \
    acc[(RH)*4+1][1] = __builtin_amdgcn_mfma_f32_16x16x32_bf16(af1, bfr1, acc[(RH)*4+1][1], 0,0,0); \
    acc[(RH)*4+2][1] = __builtin_amdgcn_mfma_f32_16x16x32_bf16(af2, bfr1, acc[(RH)*4+2][1], 0,0,0); \
    acc[(RH)*4+3][1] = __builtin_amdgcn_mfma_f32_16x16x32_bf16(af3, bfr1, acc[(RH)*4+3][1], 0,0,0); \
    acc[(RH)*4+0][2] = __builtin_amdgcn_mfma_f32_16x16x32_bf16(af0, bfr2, acc[(RH)*4+0][2], 0,0,0); \
    acc[(RH)*4+1][2] = __builtin_amdgcn_mfma_f32_16x16x32_bf16(af1, bfr2, acc[(RH)*4+1][2], 0,0,0); \
    acc[(RH)*4+2][2] = __builtin_amdgcn_mfma_f32_16x16x32_bf16(af2, bfr2, acc[(RH)*4+2][2], 0,0,0); \
    acc[(RH)*4+3][2] = __builtin_amdgcn_mfma_f32_16x16x32_bf16(af3, bfr2, acc[(RH)*4+3][2], 0,0,0); \
    acc[(RH)*4+0][3] = __builtin_amdgcn_mfma_f32_16x16x32_bf16(af0, bfr3, acc[(RH)*4+0][3], 0,0,0); \
    acc[(RH)*4+1][3] = __builtin_amdgcn_mfma_f32_16x16x32_bf16(af1, bfr3, acc[(RH)*4+1][3], 0,0,0); \
    acc[(RH)*4+2][3] = __builtin_amdgcn_mfma_f32_16x16x32_bf16(af2, bfr3, acc[(RH)*4+2][3], 0,0,0); \
    acc[(RH)*4+3][3] = __builtin_amdgcn_mfma_f32_16x16x32_bf16(af3, bfr3, acc[(RH)*4+3][3], 0,0,0); \
    __builtin_amdgcn_s_setprio(0); \
    if (VM) { asm volatile("s_waitcnt vmcnt(4)" ::: "memory"); } \
    __builtin_amdgcn_s_barrier(); \
}

template<int KD, int ND, bool GATHER>
__global__ __launch_bounds__(512, 2)
void gemm8_kernel(const bf16* __restrict__ Ab, const bf16* __restrict__ Bw,
                  const float* __restrict__ bp, const int* __restrict__ counts,
                  const int* __restrict__ offs, const int* __restrict__ tlist,
                  bf16* __restrict__ outp)
{
    extern __shared__ char smem[];
    constexpr int NT  = KD / 64;
    constexpr int NB  = ND / 256;
    constexpr int NWG = NB * 32 * NE;

    const int bid = blockIdx.x;
    const int wg  = (bid & 7) * (NWG / 8) + (bid >> 3);   // bijective XCD remap (T1)
    const int n0  = (wg % NB) * 256;
    const int m0  = ((wg / NB) & 31) * 256;
    const int e   = wg / (NB * 32);
    const int cnt = counts[e];
    if (m0 >= cnt) return;
    const int ofe = offs[e];

    const int t = threadIdx.x;
    int* toks = (int*)(smem + 131072);
    if constexpr (GATHER) {
        if (t < 256) {
            int slot = m0 + t;
            toks[t] = tlist[e*CAP + (slot < cnt ? slot : cnt-1)];
        }
        __syncthreads();
    }

    // staging sources: chunk c = l*512+t -> row c>>2, c16 = c&3, source col16 pre-swizzled
    const int r0i = t >> 2, r1i = 128 + (t >> 2);
    const int s0w = (t & 3) ^ (r0i & 3) ^ ((r0i >> 2) & 3);
    const int s1w = (t & 3) ^ (r1i & 3) ^ ((r1i >> 2) & 3);
    const bf16 *aSrc0, *aSrc1;
    if constexpr (GATHER) {
        aSrc0 = Ab + (size_t)toks[r0i] * KD + s0w * 8;
        aSrc1 = Ab + (size_t)toks[r1i] * KD + s1w * 8;
    } else {
        int a0 = m0 + r0i; if (a0 > cnt - 1) a0 = cnt - 1;
        int a1 = m0 + r1i; if (a1 > cnt - 1) a1 = cnt - 1;
        aSrc0 = Ab + (size_t)(ofe + a0) * KD + s0w * 8;
        aSrc1 = Ab + (size_t)(ofe + a1) * KD + s1w * 8;
    }
    const bf16* bSrc0 = Bw + ((size_t)e * ND + n0 + r0i) * KD + s0w * 8;
    const bf16* bSrc1 = Bw + ((size_t)e * ND + n0 + r1i) * KD + s1w * 8;

    // fragment ds_read offsets (swizzled)
    const int lane = t & 63, wv = t >> 6;
    const int wr = wv >> 2, wc = wv & 3;          // 2M x 4N waves
    const int fr = lane & 15, fq = lane >> 4;
    int aoff[8], boff[4];
    #pragma unroll
    for (int i = 0; i < 8; ++i) {
        int r = wr*128 + i*16 + fr;
        aoff[i] = r*64 + ((fq ^ (r & 3) ^ ((r >> 2) & 3)) << 4);
    }
    #pragma unroll
    for (int j = 0; j < 4; ++j) {
        int rn = wc*64 + j*16 + fr;
        boff[j] = rn*64 + ((fq ^ (rn & 3) ^ ((rn >> 2) & 3)) << 4);
    }

    f32x4 acc[8][4] = {};
    bf16x8 bfr0 = {}, bfr1 = {}, bfr2 = {}, bfr3 = {};

    // prologue: stage tile 0 fully; keep k1 halves in flight (counted vmcnt)
    STG_A(0, 0, 0); STG_B(0, 0, 0); STG_A(0, 1, 0); STG_B(0, 1, 0);
    asm volatile("s_waitcnt vmcnt(4)" ::: "memory");
    __builtin_amdgcn_s_barrier();

    for (int tt = 0; tt < NT; tt += 2) {
        {   // tile tt in buf0; stage tile tt+1 into buf1
            const int tn = (tt + 1 < NT) ? tt + 1 : tt;
            PHASE(0, 0, 0, STG_A(1, 0, tn), 0)
            PHASE(0, 0, 1, STG_B(1, 0, tn), 1)
            PHASE(0, 1, 0, STG_A(1, 1, tn), 0)
            PHASE(0, 1, 1, STG_B(1, 1, tn), 1)
        }
        {   // tile tt+1 in buf1; stage tile tt+2 into buf0
            const int tn = (tt + 2 < NT) ? tt + 2 : tt + 1;
            PHASE(1, 0, 0, STG_A(0, 0, tn), 0)
            PHASE(1, 0, 1, STG_B(0, 0, tn), 1)
            PHASE(1, 1, 0, STG_A(0, 1, tn), 0)
            PHASE(1, 1, 1, STG_B(0, 1, tn), 1)
        }
    }

    // epilogue
    float bias[4];
    #pragma unroll
    for (int j = 0; j < 4; ++j) bias[j] = bp[(size_t)e * ND + n0 + wc*64 + j*16 + fr];
    #pragma unroll
    for (int i = 0; i < 8; ++i) {
        #pragma unroll
        for (int rr = 0; rr < 4; ++rr) {
            int slot = m0 + wr*128 + i*16 + fq*4 + rr;
            if (slot < cnt) {
                bf16* orow = outp + (size_t)(ofe + slot) * ND + n0 + wc*64 + fr;
                #pragma unroll
                for (int j = 0; j < 4; ++j) {
                    float v = acc[i][j][rr] + bias[j];
                    if (GATHER) v = fmaxf(v, 0.f);      // relu fused (gemm1 only)
                    orow[j*16] = (bf16)v;
                }
            }
        }
    }
}

// ---------------------------------------------------------------- combine: out[t] = w0*y[row0] + w1*y[row1]
__global__ __launch_bounds__(256)
void combine_kernel(const bf16* __restrict__ yb, const int* __restrict__ pairpos,
                    const float* __restrict__ tokw, const int* __restrict__ offs,
                    float* __restrict__ out)
{
    const int i   = blockIdx.x * 256 + threadIdx.x;   // 4 floats each
    const int tok = i >> 8;
    const int d4  = (i & 255) * 4;
    int p0 = pairpos[2*tok], p1 = pairpos[2*tok+1];
    float w0 = tokw[2*tok],  w1 = tokw[2*tok+1];
    size_t r0 = (size_t)offs[p0 >> 13] + (p0 & 8191);
    size_t r1 = (size_t)offs[p1 >> 13] + (p1 & 8191);
    bf16x4 y0 = *(const bf16x4*)&yb[r0*DM + d4];
    bf16x4 y1 = *(const bf16x4*)&yb[r1*DM + d4];
    float4 o;
    o.x = w0*(float)y0[0] + w1*(float)y1[0];
    o.y = w0*(float)y0[1] + w1*(float)y1[1];
    o.z = w0*(float)y0[2] + w1*(float)y1[2];
    o.w = w0*(float)y0[3] + w1*(float)y1[3];
    *(float4*)&out[(size_t)tok*DM + d4] = o;
}

// ---------------------------------------------------------------- launch
extern "C" void kernel_launch(void* const* d_in, const int* in_sizes, int n_in,
                              void* d_out, int out_size, void* d_ws, size_t ws_size,
                              hipStream_t stream)
{
    const float* x  = (const float*)d_in[0];
    const float* Wg = (const float*)d_in[1];
    const float* bg = (const float*)d_in[2];
    const float* W1 = (const float*)d_in[3];
    const float* b1 = (const float*)d_in[4];
    const float* W2 = (const float*)d_in[5];
    const float* b2 = (const float*)d_in[6];
    float* out = (float*)d_out;

    char* wsb = (char*)d_ws;
    int*   counts  = (int*)  (wsb + CNT_OFF);
    int*   offs    = (int*)  (wsb + OFFS_OFF);
    float* usage   = (float*)(wsb + USAGE_OFF);
    int*   tlist   = (int*)  (wsb + TLIST_OFF);
    int*   tokexp  = (int*)  (wsb + TOKEXP_OFF);
    float* tokw    = (float*)(wsb + TOKW_OFF);
    int*   pairpos = (int*)  (wsb + PAIR_OFF);
    bf16*  xb      = (bf16*) (wsb + XB_OFF);
    bf16*  w1t     = (bf16*) (wsb + W1T_OFF);
    bf16*  w2t     = (bf16*) (wsb + W2T_OFF);
    bf16*  hbuf    = (bf16*) (wsb + H_OFF);
    bf16*  ybuf    = (bf16*) (wsb + YB_OFF);

    hipMemsetAsync(wsb, 0, 96, stream);   // counts, offs, usage

    gate_kernel<<<512, 1024, 0, stream>>>(x, Wg, bg, tokexp, tokw, usage);
    build_lists_kernel<<<32, 256, 0, stream>>>(tokexp, tokw, counts, tlist, pairpos);
    offsets_aux_kernel<<<1, 64, 0, stream>>>(counts, usage, offs, out + 8388608);

    cvt_x_kernel<<<8192, 256, 0, stream>>>(x, xb);
    transpose_cvt_kernel<<<dim3(64, 16, NE), 256, 0, stream>>>(W1, w1t, DM, DFF);
    transpose_cvt_kernel<<<dim3(16, 64, NE), 256, 0, stream>>>(W2, w2t, DFF, DM);

    const int smem_bytes = 132096;   // 128 KiB tiles + toks
    hipFuncSetAttribute(reinterpret_cast<const void*>(&gemm8_kernel<DM, DFF, true>),
                        hipFuncAttributeMaxDynamicSharedMemorySize, smem_bytes);
    hipFuncSetAttribute(reinterpret_cast<const void*>(&gemm8_kernel<DFF, DM, false>),
                        hipFuncAttributeMaxDynamicSharedMemorySize, smem_bytes);

    gemm8_kernel<DM, DFF, true><<<16*32*NE, 512, smem_bytes, stream>>>(
        xb, w1t, b1, counts, offs, tlist, hbuf);
    gemm8_kernel<DFF, DM, false><<<4*32*NE, 512, smem_bytes, stream>>>(
        hbuf, w2t, b2, counts, offs, nullptr, ybuf);

    combine_kernel<<<8192, 256, 0, stream>>>(ybuf, pairpos, tokw, offs, out);
}